// Round 2
// baseline (3814.356 us; speedup 1.0000x reference)
//
#include <hip/hip_runtime.h>
#include <cstddef>

// Problem constants (B, L, D, H, HD) = (2, 2048, 768, 12, 64)
#define Bc   2
#define Lc   2048
#define Dc   768
#define Hc   12
#define HDc  64
#define Mrows (Bc * Lc)          // 4096 rows for all (b,l) GEMMs

__device__ __forceinline__ float silu_f(float x) {
    return x / (1.0f + __expf(-x));
}

// C = A (M x K, row-major) * W^T (N x K, row-major)  [einsum 'mk,nk->mn']
// SILU: apply silu to result. PERM: scatter store to (B,H,L,HD) layout.
template<bool SILU, bool PERM>
__global__ __launch_bounds__(256)
void gemm_nt(const float* __restrict__ A, const float* __restrict__ W,
             float* __restrict__ C, int Kdim, int Ndim) {
    __shared__ float As[16][68];   // [k][m]
    __shared__ float Ws[16][68];   // [k][n]
    const int tid = threadIdx.x;
    const int tx = tid & 15, ty = tid >> 4;
    const int m0 = blockIdx.y * 64, n0 = blockIdx.x * 64;
    const int lrow = tid >> 2;          // 0..63: tile row this thread stages
    const int lk   = (tid & 3) << 2;    // 0,4,8,12: k offset (one float4)
    float acc[4][4] = {};

    const float* Ap = A + (size_t)(m0 + lrow) * Kdim + lk;
    const float* Wp = W + (size_t)(n0 + lrow) * Kdim + lk;

    for (int k0 = 0; k0 < Kdim; k0 += 16) {
        const float4 av = *(const float4*)(Ap + k0);
        const float4 wv = *(const float4*)(Wp + k0);
        __syncthreads();                 // previous iter done reading LDS
        As[lk + 0][lrow] = av.x; As[lk + 1][lrow] = av.y;
        As[lk + 2][lrow] = av.z; As[lk + 3][lrow] = av.w;
        Ws[lk + 0][lrow] = wv.x; Ws[lk + 1][lrow] = wv.y;
        Ws[lk + 2][lrow] = wv.z; Ws[lk + 3][lrow] = wv.w;
        __syncthreads();
#pragma unroll
        for (int kk = 0; kk < 16; ++kk) {
            const float4 a4 = *(const float4*)(&As[kk][ty << 2]);
            const float4 b4 = *(const float4*)(&Ws[kk][tx << 2]);
            const float a[4] = {a4.x, a4.y, a4.z, a4.w};
            const float b[4] = {b4.x, b4.y, b4.z, b4.w};
#pragma unroll
            for (int i = 0; i < 4; ++i)
#pragma unroll
                for (int j = 0; j < 4; ++j)
                    acc[i][j] += a[i] * b[j];
        }
    }

#pragma unroll
    for (int i = 0; i < 4; ++i) {
        const int row  = m0 + (ty << 2) + i;
        const int col0 = n0 + (tx << 2);
        float v0 = acc[i][0], v1 = acc[i][1], v2 = acc[i][2], v3 = acc[i][3];
        if (SILU) { v0 = silu_f(v0); v1 = silu_f(v1); v2 = silu_f(v2); v3 = silu_f(v3); }
        const float4 o = make_float4(v0, v1, v2, v3);
        if (PERM) {
            const int b = row >> 11, l = row & (Lc - 1);
            const int h = col0 >> 6, hd = col0 & 63;
            *(float4*)(C + ((((size_t)b * Hc + h) * Lc + l) * HDc + hd)) = o;
        } else {
            *(float4*)(C + (size_t)row * Ndim + col0) = o;
        }
    }
}

// In-place RoPE on q and k, layout (B,H,L,HD).
__global__ __launch_bounds__(256)
void rope_kernel(float* __restrict__ q, float* __restrict__ k,
                 const float* __restrict__ cosb, const float* __restrict__ sinb) {
    const int idx = blockIdx.x * blockDim.x + threadIdx.x;
    const int total = Bc * Hc * Lc * 32;
    if (idx >= total) return;
    const int hd = idx & 31;
    const int l  = (idx >> 5) & (Lc - 1);
    const int h  = (idx >> 16) % Hc;
    const int b  = idx / (32 * Lc * Hc);
    float* arr = (blockIdx.y == 0) ? q : k;
    const size_t base  = (((size_t)b * Hc + h) * Lc + l) * HDc;
    const size_t cbase = ((size_t)b * Lc + l) * HDc;
    const float x1 = arr[base + hd];
    const float x2 = arr[base + hd + 32];
    const float c1 = cosb[cbase + hd],      s1 = sinb[cbase + hd];
    const float c2 = cosb[cbase + hd + 32], s2 = sinb[cbase + hd + 32];
    arr[base + hd]      = x1 * c1 - x2 * s1;
    arr[base + hd + 32] = x2 * c2 + x1 * s2;
}

// Fused attention: per (b,h,q-tile of 64): S = q.k^T (lower tri only),
// silu(S)/L -> write to attn output AND accumulate S@V.
__global__ __launch_bounds__(256)
void attn_kernel(const float* __restrict__ q, const float* __restrict__ k,
                 const float* __restrict__ v, float* __restrict__ attn_out,
                 float* __restrict__ out_ws) {
    __shared__ float Qs[64][68];    // [hd][qi]  (transposed)
    __shared__ float KSs[64][68];   // phase1: K^T [hd][kj]; phase2: S^T [kj][qi]
    __shared__ float Vs[64][68];    // [kj][hd]
    const int tid = threadIdx.x;
    const int tx = tid & 15, ty = tid >> 4;
    const int qt = blockIdx.x;
    const int bh = blockIdx.y;
    const int b = bh / Hc, h = bh % Hc;
    const size_t qkv_base = (size_t)bh * Lc * HDc;
    const float invL = 1.0f / (float)Lc;

    // Stage Q tile transposed: 64x64 floats = 1024 float4 -> 4 per thread
    {
        const float* qp = q + qkv_base + (size_t)(qt * 64) * HDc;
#pragma unroll
        for (int p = 0; p < 4; ++p) {
            const int f = tid + p * 256;
            const int row = f >> 4, c4 = (f & 15) << 2;
            const float4 t = *(const float4*)(qp + (size_t)row * HDc + c4);
            Qs[c4 + 0][row] = t.x; Qs[c4 + 1][row] = t.y;
            Qs[c4 + 2][row] = t.z; Qs[c4 + 3][row] = t.w;
        }
    }

    float out_acc[4][4] = {};
    float* attn_base = attn_out + (size_t)bh * Lc * Lc;

    for (int kt = 0; kt <= qt; ++kt) {
        __syncthreads();   // previous iter done reading KSs/Vs (also covers Q staging)
        {
            const float* kp = k + qkv_base + (size_t)(kt * 64) * HDc;
            const float* vp = v + qkv_base + (size_t)(kt * 64) * HDc;
#pragma unroll
            for (int p = 0; p < 4; ++p) {
                const int f = tid + p * 256;
                const int row = f >> 4, c4 = (f & 15) << 2;
                const float4 tk = *(const float4*)(kp + (size_t)row * HDc + c4);
                KSs[c4 + 0][row] = tk.x; KSs[c4 + 1][row] = tk.y;
                KSs[c4 + 2][row] = tk.z; KSs[c4 + 3][row] = tk.w;
                *(float4*)(&Vs[row][c4]) = *(const float4*)(vp + (size_t)row * HDc + c4);
            }
        }
        __syncthreads();

        // Phase 1: S[qi][kj] = sum_hd Q^T[hd][qi] * K^T[hd][kj]
        float s[4][4] = {};
#pragma unroll
        for (int kk = 0; kk < 64; ++kk) {
            const float4 a4 = *(const float4*)(&Qs[kk][ty << 2]);
            const float4 b4 = *(const float4*)(&KSs[kk][tx << 2]);
            const float a[4] = {a4.x, a4.y, a4.z, a4.w};
            const float bb[4] = {b4.x, b4.y, b4.z, b4.w};
#pragma unroll
            for (int i = 0; i < 4; ++i)
#pragma unroll
                for (int j = 0; j < 4; ++j)
                    s[i][j] += a[i] * bb[j];
        }
        __syncthreads();   // done reading KSs as K^T; reuse it for S^T

        const bool diag = (kt == qt);
#pragma unroll
        for (int i = 0; i < 4; ++i) {
            const int qi = (ty << 2) + i, gi = qt * 64 + qi;
            float vals[4];
#pragma unroll
            for (int j = 0; j < 4; ++j) {
                const int kj = (tx << 2) + j, gj = kt * 64 + kj;
                float val = s[i][j];
                val = (diag && gj > gi) ? 0.0f : silu_f(val) * invL;
                vals[j] = val;
                KSs[kj][qi] = val;     // S^T for phase 2
            }
            *(float4*)(attn_base + (size_t)gi * Lc + kt * 64 + (tx << 2)) =
                make_float4(vals[0], vals[1], vals[2], vals[3]);
        }
        __syncthreads();

        // Phase 2: out[qi][hd] += sum_kj S^T[kj][qi] * V[kj][hd]
#pragma unroll
        for (int kk = 0; kk < 64; ++kk) {
            const float4 a4 = *(const float4*)(&KSs[kk][ty << 2]);
            const float4 b4 = *(const float4*)(&Vs[kk][tx << 2]);
            const float a[4] = {a4.x, a4.y, a4.z, a4.w};
            const float bb[4] = {b4.x, b4.y, b4.z, b4.w};
#pragma unroll
            for (int i = 0; i < 4; ++i)
#pragma unroll
                for (int j = 0; j < 4; ++j)
                    out_acc[i][j] += a[i] * bb[j];
        }
    }

    // Zero-fill strictly-upper tiles (silu(-1e9)/L == -0.0)
#pragma unroll 1
    for (int kt = qt + 1; kt < Lc / 64; ++kt) {
        const float4 z = make_float4(0.f, 0.f, 0.f, 0.f);
#pragma unroll
        for (int i = 0; i < 4; ++i) {
            const int gi = qt * 64 + (ty << 2) + i;
            *(float4*)(attn_base + (size_t)gi * Lc + kt * 64 + (tx << 2)) = z;
        }
    }

    // out_ws layout (b, l, h*64+hd) for the final projection GEMM
#pragma unroll
    for (int i = 0; i < 4; ++i) {
        const int gi = qt * 64 + (ty << 2) + i;
        *(float4*)(out_ws + ((size_t)b * Lc + gi) * Dc + h * HDc + (tx << 2)) =
            make_float4(out_acc[i][0], out_acc[i][1], out_acc[i][2], out_acc[i][3]);
    }
}

extern "C" void kernel_launch(void* const* d_in, const int* in_sizes, int n_in,
                              void* d_out, int out_size, void* d_ws, size_t ws_size,
                              hipStream_t stream) {
    const float* hs   = (const float*)d_in[0];
    const float* cosb = (const float*)d_in[2];
    const float* sinb = (const float*)d_in[3];
    const float* Wq   = (const float*)d_in[4];
    const float* Wk   = (const float*)d_in[5];
    const float* Wv   = (const float*)d_in[6];
    const float* Wo   = (const float*)d_in[7];

    float* attn_output = (float*)d_out;                         // (B,L,D)
    float* attn        = attn_output + (size_t)Mrows * Dc;      // (B,H,L,L)

    const size_t seg = (size_t)Bc * Hc * Lc * HDc;
    float* q_ = (float*)d_ws;
    float* k_ = q_ + seg;
    float* v_ = k_ + seg;
    float* o_ = v_ + seg;   // (B, L, H*HD) staging for output projection

    const dim3 blk(256);
    const dim3 ggrid(Dc / 64, Mrows / 64);      // (12, 64)

    gemm_nt<true,  true ><<<ggrid, blk, 0, stream>>>(hs, Wq, q_, Dc, Dc);
    gemm_nt<true,  true ><<<ggrid, blk, 0, stream>>>(hs, Wk, k_, Dc, Dc);
    gemm_nt<true,  true ><<<ggrid, blk, 0, stream>>>(hs, Wv, v_, Dc, Dc);

    const int total = Bc * Hc * Lc * 32;
    rope_kernel<<<dim3((total + 255) / 256, 2), blk, 0, stream>>>(q_, k_, cosb, sinb);

    attn_kernel<<<dim3(Lc / 64, Bc * Hc), blk, 0, stream>>>(q_, k_, v_, attn, o_);

    gemm_nt<false, false><<<ggrid, blk, 0, stream>>>(o_, Wo, attn_output, Dc, Dc);
}

// Round 3
// 873.208 us; speedup vs baseline: 4.3682x; 4.3682x over previous
//
#include <hip/hip_runtime.h>
#include <cstddef>

// Problem constants (B, L, D, H, HD) = (2, 2048, 768, 12, 64)
#define Bc   2
#define Lc   2048
#define Dc   768
#define Hc   12
#define HDc  64
#define Mrows (Bc * Lc)

typedef __attribute__((ext_vector_type(8))) short short8;
typedef __attribute__((ext_vector_type(4))) float floatx4;

__device__ __forceinline__ float silu_f(float x) {
    return x / (1.0f + __expf(-x));
}
__device__ __forceinline__ unsigned short f2bf(float x) {
    unsigned int u = __float_as_uint(x);
    u = (u + 0x7FFFu + ((u >> 16) & 1u)) >> 16;   // RNE
    return (unsigned short)u;
}
__device__ __forceinline__ float bf2f(unsigned short h) {
    return __uint_as_float(((unsigned int)h) << 16);
}

// ---------------- fp32 projection GEMM (unchanged this round) ----------------
template<bool SILU, bool PERM>
__global__ __launch_bounds__(256)
void gemm_nt(const float* __restrict__ A, const float* __restrict__ W,
             float* __restrict__ C, int Kdim, int Ndim) {
    __shared__ float As[16][68];
    __shared__ float Ws[16][68];
    const int tid = threadIdx.x;
    const int tx = tid & 15, ty = tid >> 4;
    const int m0 = blockIdx.y * 64, n0 = blockIdx.x * 64;
    const int lrow = tid >> 2;
    const int lk   = (tid & 3) << 2;
    float acc[4][4] = {};

    const float* Ap = A + (size_t)(m0 + lrow) * Kdim + lk;
    const float* Wp = W + (size_t)(n0 + lrow) * Kdim + lk;

    for (int k0 = 0; k0 < Kdim; k0 += 16) {
        const float4 av = *(const float4*)(Ap + k0);
        const float4 wv = *(const float4*)(Wp + k0);
        __syncthreads();
        As[lk + 0][lrow] = av.x; As[lk + 1][lrow] = av.y;
        As[lk + 2][lrow] = av.z; As[lk + 3][lrow] = av.w;
        Ws[lk + 0][lrow] = wv.x; Ws[lk + 1][lrow] = wv.y;
        Ws[lk + 2][lrow] = wv.z; Ws[lk + 3][lrow] = wv.w;
        __syncthreads();
#pragma unroll
        for (int kk = 0; kk < 16; ++kk) {
            const float4 a4 = *(const float4*)(&As[kk][ty << 2]);
            const float4 b4 = *(const float4*)(&Ws[kk][tx << 2]);
            const float a[4] = {a4.x, a4.y, a4.z, a4.w};
            const float b[4] = {b4.x, b4.y, b4.z, b4.w};
#pragma unroll
            for (int i = 0; i < 4; ++i)
#pragma unroll
                for (int j = 0; j < 4; ++j)
                    acc[i][j] += a[i] * b[j];
        }
    }

#pragma unroll
    for (int i = 0; i < 4; ++i) {
        const int row  = m0 + (ty << 2) + i;
        const int col0 = n0 + (tx << 2);
        float v0 = acc[i][0], v1 = acc[i][1], v2 = acc[i][2], v3 = acc[i][3];
        if (SILU) { v0 = silu_f(v0); v1 = silu_f(v1); v2 = silu_f(v2); v3 = silu_f(v3); }
        const float4 o = make_float4(v0, v1, v2, v3);
        if (PERM) {
            const int b = row >> 11, l = row & (Lc - 1);
            const int h = col0 >> 6, hd = col0 & 63;
            *(float4*)(C + ((((size_t)b * Hc + h) * Lc + l) * HDc + hd)) = o;
        } else {
            *(float4*)(C + (size_t)row * Ndim + col0) = o;
        }
    }
}

// ---------------- RoPE (unchanged) ----------------
__global__ __launch_bounds__(256)
void rope_kernel(float* __restrict__ q, float* __restrict__ k,
                 const float* __restrict__ cosb, const float* __restrict__ sinb) {
    const int idx = blockIdx.x * blockDim.x + threadIdx.x;
    const int total = Bc * Hc * Lc * 32;
    if (idx >= total) return;
    const int hd = idx & 31;
    const int l  = (idx >> 5) & (Lc - 1);
    const int h  = (idx >> 16) % Hc;
    const int b  = idx / (32 * Lc * Hc);
    float* arr = (blockIdx.y == 0) ? q : k;
    const size_t base  = (((size_t)b * Hc + h) * Lc + l) * HDc;
    const size_t cbase = ((size_t)b * Lc + l) * HDc;
    const float x1 = arr[base + hd];
    const float x2 = arr[base + hd + 32];
    const float c1 = cosb[cbase + hd],      s1 = sinb[cbase + hd];
    const float c2 = cosb[cbase + hd + 32], s2 = sinb[cbase + hd + 32];
    arr[base + hd]      = x1 * c1 - x2 * s1;
    arr[base + hd + 32] = x2 * c2 + x1 * s2;
}

// ---------------- MFMA attention ----------------
// Per (bh, qt): 4 waves, wave w owns q-rows [qt*64 + w*16, +16).
// Phase1: S = Q·K^T via bf16x3 compensated MFMA (hi/lo split, fp32 acc).
// Phase2: out += P·V via plain bf16 MFMA.
// PAD=72 ushorts keeps every b128 LDS access 16B-aligned (144 B row stride).
#define PAD 72

__global__ __launch_bounds__(256)
void attn_kernel(const float* __restrict__ q, const float* __restrict__ k,
                 const float* __restrict__ v, float* __restrict__ attn_out,
                 float* __restrict__ out_ws) {
    __shared__ unsigned short Qh[64][PAD], Ql[64][PAD];
    __shared__ unsigned short Kh[64][PAD], Kl[64][PAD];
    __shared__ unsigned short Vt[64][PAD];          // [hd][kj]
    __shared__ unsigned short Ps[64][PAD];          // [q][kj] bf16

    const int tid  = threadIdx.x;
    const int lane = tid & 63, wv = tid >> 6;
    const int m = lane & 15, quad = lane >> 4;
    const int qt = gridDim.x - 1 - blockIdx.x;      // big causal rows first
    const int bh = blockIdx.y;
    const int b = bh / Hc, h = bh % Hc;
    const size_t qkv = (size_t)bh * Lc * HDc;
    const float invL = 1.0f / (float)Lc;

    // ---- stage Q tile (hi/lo bf16), 64x64 fp32 -> 4 float4 per thread ----
    {
        const float* qp = q + qkv + (size_t)(qt * 64) * HDc;
#pragma unroll
        for (int p = 0; p < 4; ++p) {
            const int f = tid + p * 256;
            const int row = f >> 4, c4 = (f & 15) << 2;
            const float4 t = *(const float4*)(qp + row * HDc + c4);
            const float xs[4] = {t.x, t.y, t.z, t.w};
            unsigned short hh[4], ll[4];
#pragma unroll
            for (int i = 0; i < 4; ++i) {
                hh[i] = f2bf(xs[i]);
                ll[i] = f2bf(xs[i] - bf2f(hh[i]));
            }
            *(ushort4*)&Qh[row][c4] = make_ushort4(hh[0], hh[1], hh[2], hh[3]);
            *(ushort4*)&Ql[row][c4] = make_ushort4(ll[0], ll[1], ll[2], ll[3]);
        }
    }
    __syncthreads();

    // Hoisted Q fragments (A-operand: row = lane&15, k = quad*8+j)
    const short8 ah0 = *(const short8*)&Qh[wv * 16 + m][quad * 8];
    const short8 ah1 = *(const short8*)&Qh[wv * 16 + m][32 + quad * 8];
    const short8 al0 = *(const short8*)&Ql[wv * 16 + m][quad * 8];
    const short8 al1 = *(const short8*)&Ql[wv * 16 + m][32 + quad * 8];

    floatx4 oacc[4] = {{0.f,0.f,0.f,0.f},{0.f,0.f,0.f,0.f},
                       {0.f,0.f,0.f,0.f},{0.f,0.f,0.f,0.f}};
    float* attn_base = attn_out + (size_t)bh * Lc * Lc;

    for (int kt = 0; kt <= qt; ++kt) {
        __syncthreads();   // phase2 of previous iter done reading Vt/Ps
        {
            const float* kp = k + qkv + (size_t)(kt * 64) * HDc;
            const float* vp = v + qkv + (size_t)(kt * 64) * HDc;
#pragma unroll
            for (int p = 0; p < 4; ++p) {
                const int f = tid + p * 256;
                const int row = f >> 4, c4 = (f & 15) << 2;
                const float4 tk = *(const float4*)(kp + row * HDc + c4);
                const float ks[4] = {tk.x, tk.y, tk.z, tk.w};
                unsigned short hh[4], ll[4];
#pragma unroll
                for (int i = 0; i < 4; ++i) {
                    hh[i] = f2bf(ks[i]);
                    ll[i] = f2bf(ks[i] - bf2f(hh[i]));
                }
                *(ushort4*)&Kh[row][c4] = make_ushort4(hh[0], hh[1], hh[2], hh[3]);
                *(ushort4*)&Kl[row][c4] = make_ushort4(ll[0], ll[1], ll[2], ll[3]);
                const float4 tv = *(const float4*)(vp + row * HDc + c4);
                Vt[c4 + 0][row] = f2bf(tv.x);
                Vt[c4 + 1][row] = f2bf(tv.y);
                Vt[c4 + 2][row] = f2bf(tv.z);
                Vt[c4 + 3][row] = f2bf(tv.w);
            }
        }
        __syncthreads();

        // ---- Phase 1: S = Q·K^T (compensated) ----
        const bool diag = (kt == qt);
#pragma unroll
        for (int nn = 0; nn < 4; ++nn) {
            const short8 bh0 = *(const short8*)&Kh[nn * 16 + m][quad * 8];
            const short8 bh1 = *(const short8*)&Kh[nn * 16 + m][32 + quad * 8];
            const short8 bl0 = *(const short8*)&Kl[nn * 16 + m][quad * 8];
            const short8 bl1 = *(const short8*)&Kl[nn * 16 + m][32 + quad * 8];
            floatx4 s = {0.f, 0.f, 0.f, 0.f};
            s = __builtin_amdgcn_mfma_f32_16x16x32_bf16(al0, bh0, s, 0, 0, 0);
            s = __builtin_amdgcn_mfma_f32_16x16x32_bf16(al1, bh1, s, 0, 0, 0);
            s = __builtin_amdgcn_mfma_f32_16x16x32_bf16(ah0, bl0, s, 0, 0, 0);
            s = __builtin_amdgcn_mfma_f32_16x16x32_bf16(ah1, bl1, s, 0, 0, 0);
            s = __builtin_amdgcn_mfma_f32_16x16x32_bf16(ah0, bh0, s, 0, 0, 0);
            s = __builtin_amdgcn_mfma_f32_16x16x32_bf16(ah1, bh1, s, 0, 0, 0);
            // C/D layout: col = lane&15 (k-col), row = quad*4+reg (q-row)
#pragma unroll
            for (int r = 0; r < 4; ++r) {
                const int gi = qt * 64 + wv * 16 + quad * 4 + r;
                const int gj = kt * 64 + nn * 16 + m;
                float val = s[r];
                val = (diag && gj > gi) ? 0.0f : silu_f(val) * invL;
                attn_base[(size_t)gi * Lc + gj] = val;
                Ps[wv * 16 + quad * 4 + r][nn * 16 + m] = f2bf(val);
            }
        }
        __syncthreads();   // Ps complete

        // ---- Phase 2: out += P·V ----
        const short8 p0 = *(const short8*)&Ps[wv * 16 + m][quad * 8];
        const short8 p1 = *(const short8*)&Ps[wv * 16 + m][32 + quad * 8];
#pragma unroll
        for (int nn = 0; nn < 4; ++nn) {
            const short8 b0 = *(const short8*)&Vt[nn * 16 + m][quad * 8];
            const short8 b1 = *(const short8*)&Vt[nn * 16 + m][32 + quad * 8];
            oacc[nn] = __builtin_amdgcn_mfma_f32_16x16x32_bf16(p0, b0, oacc[nn], 0, 0, 0);
            oacc[nn] = __builtin_amdgcn_mfma_f32_16x16x32_bf16(p1, b1, oacc[nn], 0, 0, 0);
        }
    }

    // Zero-fill strictly-upper tiles (silu(-1e9)/L == -0.0)
    {
        const int tx = tid & 15, ty = tid >> 4;
#pragma unroll 1
        for (int kt2 = qt + 1; kt2 < Lc / 64; ++kt2) {
            const float4 z = make_float4(0.f, 0.f, 0.f, 0.f);
#pragma unroll
            for (int i = 0; i < 4; ++i) {
                const int gi = qt * 64 + (ty << 2) + i;
                *(float4*)(attn_base + (size_t)gi * Lc + kt2 * 64 + (tx << 2)) = z;
            }
        }
    }

    // out_ws (b, l, h*64+hd) for the output projection
#pragma unroll
    for (int nn = 0; nn < 4; ++nn)
#pragma unroll
        for (int r = 0; r < 4; ++r) {
            const int gi = qt * 64 + wv * 16 + quad * 4 + r;
            out_ws[((size_t)b * Lc + gi) * Dc + h * HDc + nn * 16 + m] = oacc[nn][r];
        }
}

extern "C" void kernel_launch(void* const* d_in, const int* in_sizes, int n_in,
                              void* d_out, int out_size, void* d_ws, size_t ws_size,
                              hipStream_t stream) {
    const float* hs   = (const float*)d_in[0];
    const float* cosb = (const float*)d_in[2];
    const float* sinb = (const float*)d_in[3];
    const float* Wq   = (const float*)d_in[4];
    const float* Wk   = (const float*)d_in[5];
    const float* Wv   = (const float*)d_in[6];
    const float* Wo   = (const float*)d_in[7];

    float* attn_output = (float*)d_out;                         // (B,L,D)
    float* attn        = attn_output + (size_t)Mrows * Dc;      // (B,H,L,L)

    const size_t seg = (size_t)Bc * Hc * Lc * HDc;
    float* q_ = (float*)d_ws;
    float* k_ = q_ + seg;
    float* v_ = k_ + seg;
    float* o_ = v_ + seg;

    const dim3 blk(256);
    const dim3 ggrid(Dc / 64, Mrows / 64);

    gemm_nt<true,  true ><<<ggrid, blk, 0, stream>>>(hs, Wq, q_, Dc, Dc);
    gemm_nt<true,  true ><<<ggrid, blk, 0, stream>>>(hs, Wk, k_, Dc, Dc);
    gemm_nt<true,  true ><<<ggrid, blk, 0, stream>>>(hs, Wv, v_, Dc, Dc);

    const int total = Bc * Hc * Lc * 32;
    rope_kernel<<<dim3((total + 255) / 256, 2), blk, 0, stream>>>(q_, k_, cosb, sinb);

    attn_kernel<<<dim3(Lc / 64, Bc * Hc), blk, 0, stream>>>(q_, k_, v_, attn, o_);

    gemm_nt<false, false><<<ggrid, blk, 0, stream>>>(o_, Wo, attn_output, Dc, Dc);
}

// Round 4
// 683.309 us; speedup vs baseline: 5.5822x; 1.2779x over previous
//
#include <hip/hip_runtime.h>
#include <cstddef>

// Problem constants (B, L, D, H, HD) = (2, 2048, 768, 12, 64)
#define Bc   2
#define Lc   2048
#define Dc   768
#define Hc   12
#define HDc  64
#define Mrows (Bc * Lc)
#define PAD  72   // ushorts; 144 B row stride = 9*16 B -> every b128 access stays 16B-aligned

typedef _Float16 half8 __attribute__((ext_vector_type(8)));
typedef unsigned short ushort8 __attribute__((ext_vector_type(8)));
typedef __attribute__((ext_vector_type(4))) float floatx4;

__device__ __forceinline__ float silu_f(float x) {
    return x / (1.0f + __expf(-x));
}
__device__ __forceinline__ unsigned short f2h(float x) {
    _Float16 h = (_Float16)x;                       // v_cvt_f16_f32, RNE
    return __builtin_bit_cast(unsigned short, h);
}
__device__ __forceinline__ float h2f(unsigned short u) {
    return (float)__builtin_bit_cast(_Float16, u);
}

// ---------------------------------------------------------------------------
// fp16-MFMA GEMM: C[m][n] = act( sum_k A[m][k] * W[n][k] )   (einsum 'mk,nk->mn')
// MODE 0: A fp32, silu, fp16 store to (b,h,l,hd)            [q16 / k16]
// MODE 1: A fp32, silu, fp16 store TRANSPOSED to (b,h,hd,l) [vT16]
// MODE 2: A fp16 (o16), no act, fp32 store to (b,l,Dc)      [attn_output]
// Block: 256 thr = 4 waves; tile 64x64; K = 768 in 12 chunks of 64.
// ---------------------------------------------------------------------------
template<int MODE>
__global__ __launch_bounds__(256)
void gemm_f16(const float* __restrict__ A32, const unsigned short* __restrict__ A16,
              const float* __restrict__ W, void* __restrict__ Cout) {
    __shared__ unsigned short Af[64][PAD];
    __shared__ unsigned short Wf[64][PAD];
    const int tid  = threadIdx.x;
    const int lane = tid & 63, w = tid >> 6;
    const int m    = lane & 15, quad = lane >> 4;
    const int m0 = blockIdx.y * 64, n0 = blockIdx.x * 64;

    floatx4 acc[4] = {{0.f,0.f,0.f,0.f},{0.f,0.f,0.f,0.f},
                      {0.f,0.f,0.f,0.f},{0.f,0.f,0.f,0.f}};

    for (int kc = 0; kc < Dc; kc += 64) {
        __syncthreads();
        if (MODE == 2) {
            // A already fp16: 64x64 ushorts = 512 ushort8 -> 2 per thread
#pragma unroll
            for (int p = 0; p < 2; ++p) {
                const int f = tid + p * 256;
                const int row = f >> 3, c8 = (f & 7) << 3;
                const ushort8 t = *(const ushort8*)(A16 + (size_t)(m0 + row) * Dc + kc + c8);
                *(ushort8*)&Af[row][c8] = t;
            }
        } else {
#pragma unroll
            for (int p = 0; p < 4; ++p) {
                const int f = tid + p * 256;
                const int row = f >> 4, c4 = (f & 15) << 2;
                const float4 t = *(const float4*)(A32 + (size_t)(m0 + row) * Dc + kc + c4);
                const ushort4 hh = make_ushort4(f2h(t.x), f2h(t.y), f2h(t.z), f2h(t.w));
                *(ushort4*)&Af[row][c4] = hh;
            }
        }
#pragma unroll
        for (int p = 0; p < 4; ++p) {
            const int f = tid + p * 256;
            const int row = f >> 4, c4 = (f & 15) << 2;
            const float4 t = *(const float4*)(W + (size_t)(n0 + row) * Dc + kc + c4);
            const ushort4 hh = make_ushort4(f2h(t.x), f2h(t.y), f2h(t.z), f2h(t.w));
            *(ushort4*)&Wf[row][c4] = hh;
        }
        __syncthreads();

        const half8 a0 = *(const half8*)&Af[w * 16 + m][0 * 32 + quad * 8];
        const half8 a1 = *(const half8*)&Af[w * 16 + m][1 * 32 + quad * 8];
#pragma unroll
        for (int nn = 0; nn < 4; ++nn) {
            const half8 b0 = *(const half8*)&Wf[nn * 16 + m][0 * 32 + quad * 8];
            const half8 b1 = *(const half8*)&Wf[nn * 16 + m][1 * 32 + quad * 8];
            acc[nn] = __builtin_amdgcn_mfma_f32_16x16x32_f16(a0, b0, acc[nn], 0, 0, 0);
            acc[nn] = __builtin_amdgcn_mfma_f32_16x16x32_f16(a1, b1, acc[nn], 0, 0, 0);
        }
    }

    // Epilogue. D frag: col = n0 + nn*16 + m, row = m0 + w*16 + quad*4 + r.
#pragma unroll
    for (int nn = 0; nn < 4; ++nn) {
        const int col = n0 + nn * 16 + m;
        if (MODE == 0) {
            const int h = col >> 6, hd = col & 63;
            unsigned short* q16 = (unsigned short*)Cout;
#pragma unroll
            for (int r = 0; r < 4; ++r) {
                const int row = m0 + w * 16 + quad * 4 + r;
                const int b = row >> 11, l = row & (Lc - 1);
                q16[(((size_t)(b * Hc + h) * Lc + l) * HDc) + hd] = f2h(silu_f(acc[nn][r]));
            }
        } else if (MODE == 1) {
            const int h = col >> 6, hd = col & 63;
            unsigned short* vT16 = (unsigned short*)Cout;
            const int row0 = m0 + w * 16 + quad * 4;
            const int b = row0 >> 11, l0 = row0 & (Lc - 1);
            const ushort4 hh = make_ushort4(f2h(silu_f(acc[nn][0])), f2h(silu_f(acc[nn][1])),
                                            f2h(silu_f(acc[nn][2])), f2h(silu_f(acc[nn][3])));
            *(ushort4*)(vT16 + ((size_t)(b * Hc + h) * HDc + hd) * Lc + l0) = hh;
        } else {
            float* C = (float*)Cout;
#pragma unroll
            for (int r = 0; r < 4; ++r) {
                const int row = m0 + w * 16 + quad * 4 + r;
                C[(size_t)row * Dc + col] = acc[nn][r];
            }
        }
    }
}

// ---------------- RoPE in-place on fp16 q16/k16, layout (b,h,l,hd) ----------------
__global__ __launch_bounds__(256)
void rope_kernel(unsigned short* __restrict__ q, unsigned short* __restrict__ k,
                 const float* __restrict__ cosb, const float* __restrict__ sinb) {
    const int idx = blockIdx.x * blockDim.x + threadIdx.x;
    const int total = Bc * Hc * Lc * 32;
    if (idx >= total) return;
    const int hd = idx & 31;
    const int l  = (idx >> 5) & (Lc - 1);
    const int h  = (idx >> 16) % Hc;
    const int b  = idx / (32 * Lc * Hc);
    unsigned short* arr = (blockIdx.y == 0) ? q : k;
    const size_t base  = (((size_t)b * Hc + h) * Lc + l) * HDc;
    const size_t cbase = ((size_t)b * Lc + l) * HDc;
    const float x1 = h2f(arr[base + hd]);
    const float x2 = h2f(arr[base + hd + 32]);
    const float c1 = cosb[cbase + hd],      s1 = sinb[cbase + hd];
    const float c2 = cosb[cbase + hd + 32], s2 = sinb[cbase + hd + 32];
    arr[base + hd]      = f2h(x1 * c1 - x2 * s1);
    arr[base + hd + 32] = f2h(x2 * c2 + x1 * s2);
}

// ---------------------------------------------------------------------------
// Fused attention, all fp16 MFMA.
// Phase 1 computes S^T = K · Q^T so the D-fragment holds 4 consecutive kj per
// lane -> float4 attn stores + ushort4 Ps writes.
// Phase 2: out = P · V with B-frags from pre-transposed Vt.
// ---------------------------------------------------------------------------
__global__ __launch_bounds__(256)
void attn_kernel(const unsigned short* __restrict__ q16,
                 const unsigned short* __restrict__ k16,
                 const unsigned short* __restrict__ vT16,
                 float* __restrict__ attn_out,
                 unsigned short* __restrict__ o16) {
    __shared__ unsigned short Qf[64][PAD];   // [q][hd]
    __shared__ unsigned short Kf[64][PAD];   // [kj][hd]
    __shared__ unsigned short Vt[64][PAD];   // [hd][kj]
    __shared__ unsigned short Ps[64][PAD];   // [q][kj]

    const int tid  = threadIdx.x;
    const int lane = tid & 63, w = tid >> 6;
    const int m = lane & 15, quad = lane >> 4;
    const int qt = gridDim.x - 1 - blockIdx.x;      // big causal rows first
    const int bh = blockIdx.y;
    const int b = bh / Hc, h = bh % Hc;
    const size_t qkv = (size_t)bh * Lc * HDc;
    const float invL = 1.0f / (float)Lc;

    // Stage Q tile (fp16, 8 KB): 512 ushort8 -> 2 per thread
    {
        const unsigned short* qp = q16 + qkv + (size_t)(qt * 64) * HDc;
#pragma unroll
        for (int p = 0; p < 2; ++p) {
            const int f = tid + p * 256;
            const int row = f >> 3, c8 = (f & 7) << 3;
            *(ushort8*)&Qf[row][c8] = *(const ushort8*)(qp + row * HDc + c8);
        }
    }
    __syncthreads();

    // Q as B-operand (fixed per wave): n = q = w*16 + m, k = hd
    const half8 bq0 = *(const half8*)&Qf[w * 16 + m][0 * 32 + quad * 8];
    const half8 bq1 = *(const half8*)&Qf[w * 16 + m][1 * 32 + quad * 8];

    floatx4 oacc[4] = {{0.f,0.f,0.f,0.f},{0.f,0.f,0.f,0.f},
                       {0.f,0.f,0.f,0.f},{0.f,0.f,0.f,0.f}};
    float* attn_base = attn_out + (size_t)bh * Lc * Lc;

    for (int kt = 0; kt <= qt; ++kt) {
        __syncthreads();   // previous iter done with Kf/Vt/Ps
        {
            const unsigned short* kp = k16 + qkv + (size_t)(kt * 64) * HDc;
            const unsigned short* vp = vT16 + (size_t)bh * HDc * Lc + kt * 64;
#pragma unroll
            for (int p = 0; p < 2; ++p) {
                const int f = tid + p * 256;
                const int row = f >> 3, c8 = (f & 7) << 3;
                *(ushort8*)&Kf[row][c8] = *(const ushort8*)(kp + row * HDc + c8);
                *(ushort8*)&Vt[row][c8] = *(const ushort8*)(vp + (size_t)row * Lc + c8);
            }
        }
        __syncthreads();

        // ---- Phase 1: S^T[kj][q] = sum_hd K[kj][hd] * Q[q][hd] ----
        const bool diag = (kt == qt);
        const int gi = qt * 64 + w * 16 + m;         // this lane's q row
#pragma unroll
        for (int mm = 0; mm < 4; ++mm) {
            const half8 ak0 = *(const half8*)&Kf[mm * 16 + m][0 * 32 + quad * 8];
            const half8 ak1 = *(const half8*)&Kf[mm * 16 + m][1 * 32 + quad * 8];
            floatx4 s = {0.f, 0.f, 0.f, 0.f};
            s = __builtin_amdgcn_mfma_f32_16x16x32_f16(ak0, bq0, s, 0, 0, 0);
            s = __builtin_amdgcn_mfma_f32_16x16x32_f16(ak1, bq1, s, 0, 0, 0);
            // D: col = q = w*16+m (fixed), row = kj = mm*16 + quad*4 + r
            const int kj0 = mm * 16 + quad * 4;
            const int gj0 = kt * 64 + kj0;
            float v[4];
#pragma unroll
            for (int r = 0; r < 4; ++r) {
                float val = s[r];
                v[r] = (diag && (gj0 + r) > gi) ? 0.0f : silu_f(val) * invL;
            }
            *(float4*)(attn_base + (size_t)gi * Lc + gj0) = make_float4(v[0], v[1], v[2], v[3]);
            *(ushort4*)&Ps[w * 16 + m][kj0] = make_ushort4(f2h(v[0]), f2h(v[1]), f2h(v[2]), f2h(v[3]));
        }
        __syncthreads();   // Ps complete

        // ---- Phase 2: out[q][hd] += sum_kj P[q][kj] * V[kj][hd] ----
        const half8 ap0 = *(const half8*)&Ps[w * 16 + m][0 * 32 + quad * 8];
        const half8 ap1 = *(const half8*)&Ps[w * 16 + m][1 * 32 + quad * 8];
#pragma unroll
        for (int nn = 0; nn < 4; ++nn) {
            const half8 bv0 = *(const half8*)&Vt[nn * 16 + m][0 * 32 + quad * 8];
            const half8 bv1 = *(const half8*)&Vt[nn * 16 + m][1 * 32 + quad * 8];
            oacc[nn] = __builtin_amdgcn_mfma_f32_16x16x32_f16(ap0, bv0, oacc[nn], 0, 0, 0);
            oacc[nn] = __builtin_amdgcn_mfma_f32_16x16x32_f16(ap1, bv1, oacc[nn], 0, 0, 0);
        }
    }

    // Zero-fill strictly-upper tiles (silu(-1e9)/L == -0.0)
    {
        const int tx = tid & 15, ty = tid >> 4;
#pragma unroll 1
        for (int kt2 = qt + 1; kt2 < Lc / 64; ++kt2) {
            const float4 z = make_float4(0.f, 0.f, 0.f, 0.f);
#pragma unroll
            for (int i = 0; i < 4; ++i) {
                const int gi2 = qt * 64 + (ty << 2) + i;
                *(float4*)(attn_base + (size_t)gi2 * Lc + kt2 * 64 + (tx << 2)) = z;
            }
        }
    }

    // out store: D col = hd = nn*16+m, row = q = w*16 + quad*4 + r
#pragma unroll
    for (int nn = 0; nn < 4; ++nn)
#pragma unroll
        for (int r = 0; r < 4; ++r) {
            const int gi2 = qt * 64 + w * 16 + quad * 4 + r;
            o16[((size_t)b * Lc + gi2) * Dc + h * HDc + nn * 16 + m] = f2h(oacc[nn][r]);
        }
}

extern "C" void kernel_launch(void* const* d_in, const int* in_sizes, int n_in,
                              void* d_out, int out_size, void* d_ws, size_t ws_size,
                              hipStream_t stream) {
    const float* hs   = (const float*)d_in[0];
    const float* cosb = (const float*)d_in[2];
    const float* sinb = (const float*)d_in[3];
    const float* Wq   = (const float*)d_in[4];
    const float* Wk   = (const float*)d_in[5];
    const float* Wv   = (const float*)d_in[6];
    const float* Wo   = (const float*)d_in[7];

    float* attn_output = (float*)d_out;                         // (B,L,D)
    float* attn        = attn_output + (size_t)Mrows * Dc;      // (B,H,L,L)

    const size_t seg = (size_t)Bc * Hc * Lc * HDc;              // 3,145,728 elems
    unsigned short* q16  = (unsigned short*)d_ws;
    unsigned short* k16  = q16 + seg;
    unsigned short* vT16 = k16 + seg;                           // (b,h,hd,l)
    unsigned short* o16  = vT16 + seg;                          // (b,l,Dc)

    const dim3 blk(256);
    const dim3 ggrid(Dc / 64, Mrows / 64);                      // (12, 64)

    gemm_f16<0><<<ggrid, blk, 0, stream>>>(hs, nullptr, Wq, q16);
    gemm_f16<0><<<ggrid, blk, 0, stream>>>(hs, nullptr, Wk, k16);
    gemm_f16<1><<<ggrid, blk, 0, stream>>>(hs, nullptr, Wv, vT16);

    const int total = Bc * Hc * Lc * 32;
    rope_kernel<<<dim3((total + 255) / 256, 2), blk, 0, stream>>>(q16, k16, cosb, sinb);

    attn_kernel<<<dim3(Lc / 64, Bc * Hc), blk, 0, stream>>>(q16, k16, vT16, attn, o16);

    gemm_f16<2><<<ggrid, blk, 0, stream>>>(nullptr, o16, Wo, attn_output);
}